// Round 11
// baseline (5892.004 us; speedup 1.0000x reference)
//
#include <hip/hip_runtime.h>
#include <hip/hip_bf16.h>
#include <math.h>

// LSTM (N=64, T=1024, D=H=512), persistent bf16-MFMA v5: tagged-h exchange.
//
// ws layout:
//   Wt   bf16 [2048][1024] @ 0     (4 MB)  [Wx;Wh]^T, col-major-K
//   hb32 u32  [2][64][512] @ 4MB   (256 KB) tagged h: (tag<<16)|bf16, parity-buffered
//
// 256 blocks = 4 row-groups (16 rows) x 64 j-groups (8 h-cols x 4 gates).
// 512 thr = 8 waves; wave wv owns K-slice [wv*64, +64) of BOTH x-K and h-K,
// and computes 2 col-tiles (ct=0: gates i,f; ct=1: gates o,g) -> 8 MFMA/wave.
// h exchange: producers store tagged u32 cells (sc0sc1, NO drain, NO flag);
// consumers load + retry until tag==t. ONE L3 round-trip per step.
// Parity overwrite safety: block P overwrites parity p (tag t+2) only after
// finishing step t+1, whose own tag-(t+1) loads required every peer C to have
// published t+1, which (program order) is after C's tag-t reads completed.
// Replay safety: lstm_init rewrites both parities (tag0 | 0xFFFF sentinel).

#define TT 1024
#define HH 512
#define FH 2048
#define KK 1024
#define NN 64

typedef __attribute__((ext_vector_type(8))) short bf16x8;
typedef __attribute__((ext_vector_type(4))) float f32x4;
typedef __attribute__((ext_vector_type(4))) int int4v;

__device__ __forceinline__ unsigned short f2bf(float f) {
    return __builtin_bit_cast(unsigned short, __float2bfloat16(f));
}

// ---------------- prep: Wt[col][k] = [Wx;Wh]^T bf16 ----------------
__global__ __launch_bounds__(256)
void prep_wt(const float* __restrict__ Wx, const float* __restrict__ Wh,
             unsigned short* __restrict__ Wt)
{
    __shared__ float tile[64][65];
    const int c0  = blockIdx.x * 64;
    const int k0  = blockIdx.y * 64;
    const int tid = threadIdx.x;

    #pragma unroll
    for (int it = 0; it < 16; ++it) {
        int idx = it * 256 + tid;
        int kk = idx >> 6, cc = idx & 63;
        int k = k0 + kk;
        float w = (k < 512) ? Wx[(size_t)k * FH + c0 + cc]
                            : Wh[(size_t)(k - 512) * FH + c0 + cc];
        tile[kk][cc] = w;
    }
    __syncthreads();

    #pragma unroll
    for (int it = 0; it < 8; ++it) {
        int idx = it * 256 + tid;
        int cc = idx >> 5, kp = idx & 31;
        unsigned int lo = f2bf(tile[kp * 2][cc]);
        unsigned int hi = f2bf(tile[kp * 2 + 1][cc]);
        *(unsigned int*)(Wt + (size_t)(c0 + cc) * KK + k0 + kp * 2) =
            lo | (hi << 16);
    }
}

// ---------------- init: seed parity0 = (tag0|h0), parity1 = sentinel ----------------
__global__ __launch_bounds__(256)
void lstm_init(const float* __restrict__ h0, unsigned int* __restrict__ hb32)
{
    int id = blockIdx.x * 256 + threadIdx.x;
    if (id < NN * HH) {
        unsigned int v0 = (unsigned int)f2bf(h0[id]);   // tag 0 | h0
        unsigned int v1 = 0xFFFF0000u;                  // sentinel tag
        unsigned int* p0 = hb32 + id;
        unsigned int* p1 = hb32 + NN * HH + id;
        asm volatile("global_store_dword %0, %1, off sc0 sc1" :: "v"(p0), "v"(v0) : "memory");
        asm volatile("global_store_dword %0, %1, off sc0 sc1" :: "v"(p1), "v"(v1) : "memory");
    }
}

// ---------------- persistent recurrence ----------------
__global__ __launch_bounds__(512, 2)
void lstm_persist(const float* __restrict__ x,
                  const unsigned short* __restrict__ Wt,
                  const float* __restrict__ bias,
                  float* __restrict__ out,
                  unsigned int* __restrict__ hb32)
{
    __shared__ float part[2][8][2][16][17];   // [buf][wave][ct][crow][ccol] ~35 KB

    const int tid  = threadIdx.x;
    const int wv   = tid >> 6;             // 0..7 = K-slice index
    const int lane = tid & 63;
    const int l15  = lane & 15;
    const int kh   = lane >> 4;            // 0..3

    const int rg = blockIdx.x >> 6;        // row-group 0..3
    const int jg = blockIdx.x & 63;        // j-group 0..63
    const int j0 = jg * 8;
    const int rowbase = rg * 16;

    // ---- B fragments for both col-tiles, x- and h-halves (32 VGPR) ----
    bf16x8 bx[2][2], bh[2][2];
    #pragma unroll
    for (int ct = 0; ct < 2; ++ct) {
        const int lc   = ct * 16 + l15;
        const int gate = lc >> 3;
        const int jj   = lc & 7;
        const int gcol = gate * HH + j0 + jj;
        const unsigned short* wtp = Wt + (size_t)gcol * KK + kh * 8;
        #pragma unroll
        for (int ks = 0; ks < 2; ++ks) {
            bx[ct][ks] = *(const bf16x8*)(wtp + wv * 64 + ks * 32);
            bh[ct][ks] = *(const bf16x8*)(wtp + 512 + wv * 64 + ks * 32);
        }
    }

    // A-frag addressing: row = rowbase+l15, k-slice base = wv*64 + kh*8
    const float* xbase = x + (size_t)(rowbase + l15) * TT * 512 + wv * 64 + kh * 8;
    const unsigned int* hlane = hb32 + (size_t)(rowbase + l15) * HH + wv * 64 + kh * 8;

    // gate-phase ownership (tid < 128): cell (grow_l = tid>>3, q = tid&7)
    const int grow_l = (tid >> 3) & 15;
    const int q      = tid & 7;
    const int grow   = rowbase + grow_l;
    const int gj     = j0 + q;
    float bi = 0.f, bf_ = 0.f, bo = 0.f, bg = 0.f;
    if (tid < 128) {
        bi  = bias[gj];
        bf_ = bias[HH + gj];
        bo  = bias[2 * HH + gj];
        bg  = bias[3 * HH + gj];
    }
    float c_reg = 0.f;
    float* outp = out + (size_t)grow * TT * HH + gj;
    unsigned int* hdst0 = hb32 + (size_t)grow * HH + gj;

    // ---- prologue: x fragments for t=0 ----
    int4v xw[4];
    {
        const float* xp = xbase;
        #pragma unroll
        for (int ks = 0; ks < 2; ++ks) {
            asm volatile("global_load_dwordx4 %0, %1, off" : "=v"(xw[2 * ks])     : "v"(xp + ks * 32));
            asm volatile("global_load_dwordx4 %0, %1, off" : "=v"(xw[2 * ks + 1]) : "v"(xp + ks * 32 + 4));
        }
        asm volatile("s_waitcnt vmcnt(0)" ::: "memory");
        __builtin_amdgcn_sched_barrier(0);
    }
    bf16x8 xf[2];
    #pragma unroll
    for (int ks = 0; ks < 2; ++ks) {
        float4 u = __builtin_bit_cast(float4, xw[2 * ks]);
        float4 v = __builtin_bit_cast(float4, xw[2 * ks + 1]);
        bf16x8 a;
        a[0] = (short)f2bf(u.x); a[1] = (short)f2bf(u.y);
        a[2] = (short)f2bf(u.z); a[3] = (short)f2bf(u.w);
        a[4] = (short)f2bf(v.x); a[5] = (short)f2bf(v.y);
        a[6] = (short)f2bf(v.z); a[7] = (short)f2bf(v.w);
        xf[ks] = a;
    }

    for (int t = 0; t < TT; ++t) {
        const int pb = t & 1;
        const unsigned int tg = (unsigned int)t;
        const unsigned int* hp = hlane + (size_t)pb * NN * HH;

        // ---- issue tagged h loads (4 x b128, sc0sc1) ----
        int4v hw[4];
        #pragma unroll
        for (int ks = 0; ks < 2; ++ks) {
            asm volatile("global_load_dwordx4 %0, %1, off sc0 sc1" : "=v"(hw[2 * ks])     : "v"(hp + ks * 32));
            asm volatile("global_load_dwordx4 %0, %1, off sc0 sc1" : "=v"(hw[2 * ks + 1]) : "v"(hp + ks * 32 + 4));
        }

        // ---- issue x loads for t+1 (4 x b128, plain/cached) ----
        if (t + 1 < TT) {
            const float* xp = xbase + (size_t)(t + 1) * 512;
            #pragma unroll
            for (int ks = 0; ks < 2; ++ks) {
                asm volatile("global_load_dwordx4 %0, %1, off" : "=v"(xw[2 * ks])     : "v"(xp + ks * 32));
                asm volatile("global_load_dwordx4 %0, %1, off" : "=v"(xw[2 * ks + 1]) : "v"(xp + ks * 32 + 4));
            }
        }

        // ---- x-GEMM: 2 ct x 2 ks MFMA (regs ready from previous iter) ----
        f32x4 acc0 = {0.f, 0.f, 0.f, 0.f};
        f32x4 acc1 = {0.f, 0.f, 0.f, 0.f};
        #pragma unroll
        for (int ks = 0; ks < 2; ++ks) {
            acc0 = __builtin_amdgcn_mfma_f32_16x16x32_bf16(xf[ks], bx[0][ks], acc0, 0, 0, 0);
            acc1 = __builtin_amdgcn_mfma_f32_16x16x32_bf16(xf[ks], bx[1][ks], acc1, 0, 0, 0);
        }

        // ---- wait for h loads (x loads stay in flight), tag-check + retry ----
        if (t + 1 < TT) { asm volatile("s_waitcnt vmcnt(4)" ::: "memory"); }
        else            { asm volatile("s_waitcnt vmcnt(0)" ::: "memory"); }
        __builtin_amdgcn_sched_barrier(0);

        while (true) {
            unsigned int okm = 1u;
            #pragma unroll
            for (int i = 0; i < 4; ++i) {
                #pragma unroll
                for (int e = 0; e < 4; ++e)
                    okm &= (unsigned int)((((unsigned int)hw[i][e]) >> 16) == tg);
            }
            if (__all((int)okm)) break;
            #pragma unroll
            for (int ks = 0; ks < 2; ++ks) {
                asm volatile("global_load_dwordx4 %0, %1, off sc0 sc1" : "=v"(hw[2 * ks])     : "v"(hp + ks * 32));
                asm volatile("global_load_dwordx4 %0, %1, off sc0 sc1" : "=v"(hw[2 * ks + 1]) : "v"(hp + ks * 32 + 4));
            }
            asm volatile("s_waitcnt vmcnt(0)" ::: "memory");
            __builtin_amdgcn_sched_barrier(0);
        }

        // ---- build h fragments (strip tags, pack bf16 pairs) ----
        bf16x8 hf[2];
        #pragma unroll
        for (int ks = 0; ks < 2; ++ks) {
            unsigned int d0 = ((unsigned int)hw[2 * ks][0] & 0xFFFFu) | ((unsigned int)hw[2 * ks][1] << 16);
            unsigned int d1 = ((unsigned int)hw[2 * ks][2] & 0xFFFFu) | ((unsigned int)hw[2 * ks][3] << 16);
            unsigned int d2 = ((unsigned int)hw[2 * ks + 1][0] & 0xFFFFu) | ((unsigned int)hw[2 * ks + 1][1] << 16);
            unsigned int d3 = ((unsigned int)hw[2 * ks + 1][2] & 0xFFFFu) | ((unsigned int)hw[2 * ks + 1][3] << 16);
            int4v af = {(int)d0, (int)d1, (int)d2, (int)d3};
            hf[ks] = __builtin_bit_cast(bf16x8, af);
        }

        // ---- h-GEMM ----
        #pragma unroll
        for (int ks = 0; ks < 2; ++ks) {
            acc0 = __builtin_amdgcn_mfma_f32_16x16x32_bf16(hf[ks], bh[0][ks], acc0, 0, 0, 0);
            acc1 = __builtin_amdgcn_mfma_f32_16x16x32_bf16(hf[ks], bh[1][ks], acc1, 0, 0, 0);
        }

        // ---- write partials ----
        #pragma unroll
        for (int rr = 0; rr < 4; ++rr) {
            part[pb][wv][0][kh * 4 + rr][l15] = acc0[rr];
            part[pb][wv][1][kh * 4 + rr][l15] = acc1[rr];
        }

        __syncthreads();   // the ONE barrier per step

        // ---- gates (tid < 128): reduce 8 K-slices, update state, tagged store ----
        if (tid < 128) {
            float Ai = bi, Af = bf_, Ao = bo, Ag = bg;
            #pragma unroll
            for (int w = 0; w < 8; ++w) {
                Ai += part[pb][w][0][grow_l][q];
                Af += part[pb][w][0][grow_l][q + 8];
                Ao += part[pb][w][1][grow_l][q];
                Ag += part[pb][w][1][grow_l][q + 8];
            }
            float ig = 1.f / (1.f + __expf(-Ai));
            float fg = 1.f / (1.f + __expf(-Af));
            float og = 1.f / (1.f + __expf(-Ao));
            float eg = __expf(2.f * Ag);
            float gg = 1.f - 2.f / (eg + 1.f);          // tanh(Ag)
            c_reg = fg * c_reg + ig * gg;
            float ec = __expf(2.f * c_reg);
            float tc = 1.f - 2.f / (ec + 1.f);          // tanh(c)
            float hn = og * tc;

            unsigned int hv = (((unsigned int)(t + 1)) << 16) | (unsigned int)f2bf(hn);
            unsigned int* hdst = hdst0 + (size_t)((t + 1) & 1) * NN * HH;
            asm volatile("global_store_dword %0, %1, off sc0 sc1"
                         :: "v"(hdst), "v"(hv) : "memory");
            outp[(size_t)t * HH] = hn;
        }

        // ---- convert x prefetch -> fragments for t+1 ----
        if (t + 1 < TT) {
            asm volatile("s_waitcnt vmcnt(0)" ::: "memory");
            __builtin_amdgcn_sched_barrier(0);
            #pragma unroll
            for (int ks = 0; ks < 2; ++ks) {
                float4 u = __builtin_bit_cast(float4, xw[2 * ks]);
                float4 v = __builtin_bit_cast(float4, xw[2 * ks + 1]);
                bf16x8 a;
                a[0] = (short)f2bf(u.x); a[1] = (short)f2bf(u.y);
                a[2] = (short)f2bf(u.z); a[3] = (short)f2bf(u.w);
                a[4] = (short)f2bf(v.x); a[5] = (short)f2bf(v.y);
                a[6] = (short)f2bf(v.z); a[7] = (short)f2bf(v.w);
                xf[ks] = a;
            }
        }
    }
}

extern "C" void kernel_launch(void* const* d_in, const int* in_sizes, int n_in,
                              void* d_out, int out_size, void* d_ws, size_t ws_size,
                              hipStream_t stream)
{
    const float* x  = (const float*)d_in[0];
    const float* h0 = (const float*)d_in[1];
    const float* Wx = (const float*)d_in[2];
    const float* Wh = (const float*)d_in[3];
    const float* b  = (const float*)d_in[4];
    float* out = (float*)d_out;

    char* ws = (char*)d_ws;
    unsigned short* Wt   = (unsigned short*)ws;                             // 4 MB
    unsigned int*   hb32 = (unsigned int*)(ws + (size_t)4 * 1024 * 1024);   // 256 KB

    prep_wt<<<dim3(32, 16), 256, 0, stream>>>(Wx, Wh, Wt);
    lstm_init<<<128, 256, 0, stream>>>(h0, hb32);
    lstm_persist<<<256, 512, 0, stream>>>(x, Wt, b, out, hb32);
}

// Round 12
// 3189.895 us; speedup vs baseline: 1.8471x; 1.8471x over previous
//
#include <hip/hip_runtime.h>
#include <hip/hip_bf16.h>
#include <math.h>

// LSTM (N=64, T=1024, D=H=512), persistent bf16-MFMA v6.
//
// ws layout:
//   Wt  bf16 [2048][1024] @ 0        (4 MB)   [Wx;Wh]^T, col-major-K
//   hb  bf16 [2][64][512] @ 4MB      (128 KB) h panels, parity-buffered
//   flg u32  [256][16]    @ 4MB+128K (16 KB)  words 0/1 = gate-wave flags
//
// 256 blocks = 4 row-groups (16 rows) x 64 j-groups (8 h-cols x 4 gates).
// 512 thr = 8 waves = 2 col-tiles (ct) x 4 K-quarters (kq); 4 x-MFMA + 4
// h-MFMA per wave. x fragments live in registers (plain cached loads,
// prefetched 1 step ahead). h staged once per block into a 16 KB swizzled
// LDS panel (r8's verified full-rank swizzle). Wave0-only flag poll +
// syncthreads release; dual flags published per gate wave after its own
// vmcnt(0) drain. 3 barriers/step. c-state in registers.

#define TT 1024
#define HH 512
#define FH 2048
#define KK 1024
#define NN 64

typedef __attribute__((ext_vector_type(8))) short bf16x8;
typedef __attribute__((ext_vector_type(4))) float f32x4;
typedef __attribute__((ext_vector_type(4))) int int4v;
typedef __attribute__((ext_vector_type(2))) int int2v;

__device__ __forceinline__ unsigned short f2bf(float f) {
    return __builtin_bit_cast(unsigned short, __float2bfloat16(f));
}

// ---------------- prep: Wt[col][k] = [Wx;Wh]^T bf16 ----------------
__global__ __launch_bounds__(256)
void prep_wt(const float* __restrict__ Wx, const float* __restrict__ Wh,
             unsigned short* __restrict__ Wt)
{
    __shared__ float tile[64][65];
    const int c0  = blockIdx.x * 64;
    const int k0  = blockIdx.y * 64;
    const int tid = threadIdx.x;

    #pragma unroll
    for (int it = 0; it < 16; ++it) {
        int idx = it * 256 + tid;
        int kk = idx >> 6, cc = idx & 63;
        int k = k0 + kk;
        float w = (k < 512) ? Wx[(size_t)k * FH + c0 + cc]
                            : Wh[(size_t)(k - 512) * FH + c0 + cc];
        tile[kk][cc] = w;
    }
    __syncthreads();

    #pragma unroll
    for (int it = 0; it < 8; ++it) {
        int idx = it * 256 + tid;
        int cc = idx >> 5, kp = idx & 31;
        unsigned int lo = f2bf(tile[kp * 2][cc]);
        unsigned int hi = f2bf(tile[kp * 2 + 1][cc]);
        *(unsigned int*)(Wt + (size_t)(c0 + cc) * KK + k0 + kp * 2) =
            lo | (hi << 16);
    }
}

// ---------------- init: zero flags, seed hb parity0 ----------------
__global__ __launch_bounds__(256)
void lstm_init(const float* __restrict__ h0,
               unsigned short* __restrict__ hb,
               unsigned int* __restrict__ flg)
{
    int id = blockIdx.x * 256 + threadIdx.x;
    if (id < 256 * 16) {
        unsigned int* p = flg + id;
        unsigned int z = 0u;
        asm volatile("global_store_dword %0, %1, off sc0 sc1" :: "v"(p), "v"(z) : "memory");
    }
    if (id < NN * HH) {
        unsigned int hv = (unsigned int)f2bf(h0[id]);
        unsigned short* hp = hb + id;
        asm volatile("global_store_short %0, %1, off sc0 sc1" :: "v"(hp), "v"(hv) : "memory");
    }
}

// ---------------- persistent recurrence ----------------
__global__ __launch_bounds__(512)
void lstm_persist(const float* __restrict__ x,
                  const unsigned short* __restrict__ Wt,
                  const float* __restrict__ bias,
                  float* __restrict__ out,
                  unsigned short* __restrict__ hb,
                  unsigned int* __restrict__ flg)
{
    __shared__ __align__(16) unsigned short Aph[16 * 512];  // 16 KB h panel
    __shared__ float part[8][16][17];                        // 8.7 KB partials

    const int tid  = threadIdx.x;
    const int wv   = tid >> 6;
    const int lane = tid & 63;
    const int l15  = lane & 15;
    const int kh   = lane >> 4;            // 0..3

    const int rg = blockIdx.x >> 6;        // row-group 0..3
    const int jg = blockIdx.x & 63;        // j-group 0..63
    const int j0 = jg * 8;
    const int rowbase = rg * 16;

    const int ct = wv & 1;                 // col-tile 0..1
    const int kq = wv >> 1;                // K-quarter 0..3

    const int lc   = ct * 16 + l15;        // local A-col 0..31
    const int gate = lc >> 3;
    const int jj   = lc & 7;
    const int gcol = gate * HH + j0 + jj;

    // ---- hoist B fragments (32 VGPR) ----
    const unsigned short* wtp = Wt + (size_t)gcol * KK + kh * 8;
    bf16x8 bx[4], bh[4];
    #pragma unroll
    for (int ks = 0; ks < 4; ++ks) {
        bx[ks] = *(const bf16x8*)(wtp + kq * 128 + ks * 32);
        bh[ks] = *(const bf16x8*)(wtp + 512 + kq * 128 + ks * 32);
    }

    // x addressing (reg-direct, MFMA layout; redundant across ct pair, L2-cached)
    const float* xlane = x + (size_t)(rowbase + l15) * TT * 512 + kq * 128 + kh * 8;

    // h-panel read addressing (full-rank swizzle, verified in r8)
    const int arow = l15;
    const int rsw  = ((arow & 15) << 3) | ((arow & 3) << 7);

    // h-stage coords: thread (srow = tid>>5, scol = tid&31), 32B each
    const int srow  = tid >> 5;
    const int scol  = tid & 31;
    const int rsw_s = ((srow & 15) << 3) | ((srow & 3) << 7);
    const unsigned short* hrow = hb + (size_t)(rowbase + srow) * HH + scol * 16;
    unsigned short* aps0 = Aph + srow * 512 + ((scol * 16) ^ rsw_s);
    unsigned short* aps1 = Aph + srow * 512 + (((scol * 16) + 8) ^ rsw_s);

    // gate-phase ownership (tid < 128)
    const int grow_l = (tid >> 3) & 15;
    const int q      = tid & 7;
    const int grow   = rowbase + grow_l;
    const int gj     = j0 + q;
    float bi = 0.f, bf_ = 0.f, bo = 0.f, bg = 0.f;
    if (tid < 128) {
        bi  = bias[gj];
        bf_ = bias[HH + gj];
        bo  = bias[2 * HH + gj];
        bg  = bias[3 * HH + gj];
    }
    float c_reg = 0.f;
    float* outp = out + (size_t)grow * TT * HH + gj;
    unsigned short* hdst0 = hb + (size_t)grow * HH + gj;

    unsigned int* myflag = flg + (size_t)blockIdx.x * 16 + wv;   // word 0/1
    const unsigned int* pollp = flg + (size_t)(rg * 64 + lane) * 16;

    // ---- prologue: x fragments for t=0 ----
    int4v xw[8];
    {
        #pragma unroll
        for (int ks = 0; ks < 4; ++ks) {
            asm volatile("global_load_dwordx4 %0, %1, off" : "=v"(xw[2 * ks])     : "v"(xlane + ks * 32));
            asm volatile("global_load_dwordx4 %0, %1, off" : "=v"(xw[2 * ks + 1]) : "v"(xlane + ks * 32 + 4));
        }
        asm volatile("s_waitcnt vmcnt(0)" ::: "memory");
        __builtin_amdgcn_sched_barrier(0);
    }
    bf16x8 xf[4];
    #pragma unroll
    for (int ks = 0; ks < 4; ++ks) {
        float4 u = __builtin_bit_cast(float4, xw[2 * ks]);
        float4 v = __builtin_bit_cast(float4, xw[2 * ks + 1]);
        bf16x8 a;
        a[0] = (short)f2bf(u.x); a[1] = (short)f2bf(u.y);
        a[2] = (short)f2bf(u.z); a[3] = (short)f2bf(u.w);
        a[4] = (short)f2bf(v.x); a[5] = (short)f2bf(v.y);
        a[6] = (short)f2bf(v.z); a[7] = (short)f2bf(v.w);
        xf[ks] = a;
    }

    for (int t = 0; t < TT; ++t) {
        const int pb  = t & 1;
        const int nxt = pb ^ 1;

        // ---- x-GEMM: 4 MFMA from registers (overlaps peers' publish) ----
        f32x4 accx = {0.f, 0.f, 0.f, 0.f};
        #pragma unroll
        for (int ks = 0; ks < 4; ++ks)
            accx = __builtin_amdgcn_mfma_f32_16x16x32_bf16(xf[ks], bx[ks], accx, 0, 0, 0);

        // ---- poll (wave 0 only): both flag words of all 64 producers >= t ----
        if (t > 0 && wv == 0) {
            const unsigned int tgt = (unsigned int)t;
            int2v v;
            do {
                asm volatile("global_load_dwordx2 %0, %1, off sc0 sc1\n\t"
                             "s_waitcnt vmcnt(0)"
                             : "=v"(v) : "v"(pollp) : "memory");
            } while (!__all(((unsigned int)v[0] >= tgt) & ((unsigned int)v[1] >= tgt)));
        }
        __syncthreads();   // B2: release

        // ---- stage h (16 KB once per block): 32B/thread, swizzled LDS ----
        {
            const unsigned short* hs = hrow + (size_t)pb * NN * HH;
            int4v h0v, h1v;
            asm volatile("global_load_dwordx4 %0, %2, off sc0 sc1\n\t"
                         "global_load_dwordx4 %1, %3, off sc0 sc1\n\t"
                         "s_waitcnt vmcnt(0)"
                         : "=&v"(h0v), "=&v"(h1v)
                         : "v"(hs), "v"(hs + 8) : "memory");
            __builtin_amdgcn_sched_barrier(0);
            *(int4v*)aps0 = h0v;
            *(int4v*)aps1 = h1v;
        }
        __syncthreads();   // B3: h panel visible

        // ---- h-GEMM: 4 MFMA from LDS ----
        f32x4 acch = {0.f, 0.f, 0.f, 0.f};
        #pragma unroll
        for (int ks = 0; ks < 4; ++ks) {
            bf16x8 hf = *(const bf16x8*)(Aph + arow * 512
                           + ((kq * 128 + ks * 32 + kh * 8) ^ rsw));
            acch = __builtin_amdgcn_mfma_f32_16x16x32_bf16(hf, bh[ks], acch, 0, 0, 0);
        }
        #pragma unroll
        for (int rr = 0; rr < 4; ++rr)
            part[wv][kh * 4 + rr][l15] = accx[rr] + acch[rr];
        __syncthreads();   // B4: partials ready

        // ---- gates (waves 0-1): direct reduce, state update, publish ----
        if (tid < 128) {
            float Ai = bi, Af = bf_, Ao = bo, Ag = bg;
            #pragma unroll
            for (int k2 = 0; k2 < 4; ++k2) {
                Ai += part[2 * k2][grow_l][q];
                Af += part[2 * k2][grow_l][8 + q];
                Ao += part[2 * k2 + 1][grow_l][q];
                Ag += part[2 * k2 + 1][grow_l][8 + q];
            }
            float ig = 1.f / (1.f + __expf(-Ai));
            float fg = 1.f / (1.f + __expf(-Af));
            float og = 1.f / (1.f + __expf(-Ao));
            float eg = __expf(2.f * Ag);
            float gg = 1.f - 2.f / (eg + 1.f);          // tanh(Ag)
            c_reg = fg * c_reg + ig * gg;
            float ec = __expf(2.f * c_reg);
            float tc = 1.f - 2.f / (ec + 1.f);          // tanh(c)
            float hn = og * tc;

            unsigned int hv = (unsigned int)f2bf(hn);
            unsigned short* hdst = hdst0 + (size_t)nxt * NN * HH;
            asm volatile("global_store_short %0, %1, off sc0 sc1"
                         :: "v"(hdst), "v"(hv) : "memory");
            asm volatile("s_waitcnt vmcnt(0)" ::: "memory");   // drain own h stores
            if (t + 1 < TT && lane == 0) {
                unsigned int tgt2 = (unsigned int)(t + 1);
                asm volatile("global_store_dword %0, %1, off sc0 sc1"
                             :: "v"(myflag), "v"(tgt2) : "memory");
            }
            outp[(size_t)t * HH] = hn;   // off critical path, after publish
        }

        // ---- x prefetch + convert for t+1 (all waves; overlaps peers) ----
        if (t + 1 < TT) {
            const float* xp = xlane + (size_t)(t + 1) * 512;
            #pragma unroll
            for (int ks = 0; ks < 4; ++ks) {
                asm volatile("global_load_dwordx4 %0, %1, off" : "=v"(xw[2 * ks])     : "v"(xp + ks * 32));
                asm volatile("global_load_dwordx4 %0, %1, off" : "=v"(xw[2 * ks + 1]) : "v"(xp + ks * 32 + 4));
            }
            asm volatile("s_waitcnt vmcnt(0)" ::: "memory");
            __builtin_amdgcn_sched_barrier(0);
            #pragma unroll
            for (int ks = 0; ks < 4; ++ks) {
                float4 u = __builtin_bit_cast(float4, xw[2 * ks]);
                float4 v = __builtin_bit_cast(float4, xw[2 * ks + 1]);
                bf16x8 a;
                a[0] = (short)f2bf(u.x); a[1] = (short)f2bf(u.y);
                a[2] = (short)f2bf(u.z); a[3] = (short)f2bf(u.w);
                a[4] = (short)f2bf(v.x); a[5] = (short)f2bf(v.y);
                a[6] = (short)f2bf(v.z); a[7] = (short)f2bf(v.w);
                xf[ks] = a;
            }
        }
    }
}

extern "C" void kernel_launch(void* const* d_in, const int* in_sizes, int n_in,
                              void* d_out, int out_size, void* d_ws, size_t ws_size,
                              hipStream_t stream)
{
    const float* x  = (const float*)d_in[0];
    const float* h0 = (const float*)d_in[1];
    const float* Wx = (const float*)d_in[2];
    const float* Wh = (const float*)d_in[3];
    const float* b  = (const float*)d_in[4];
    float* out = (float*)d_out;

    char* ws = (char*)d_ws;
    unsigned short* Wt  = (unsigned short*)ws;                                      // 4 MB
    unsigned short* hb  = (unsigned short*)(ws + (size_t)4 * 1024 * 1024);          // 128 KB
    unsigned int*   flg = (unsigned int*)(ws + (size_t)4 * 1024 * 1024 + 131072);   // 16 KB

    prep_wt<<<dim3(32, 16), 256, 0, stream>>>(Wx, Wh, Wt);
    lstm_init<<<128, 256, 0, stream>>>(h0, hb, flg);
    lstm_persist<<<256, 512, 0, stream>>>(x, Wt, b, out, hb, flg);
}

// Round 13
// 3184.761 us; speedup vs baseline: 1.8501x; 1.0016x over previous
//
#include <hip/hip_runtime.h>
#include <hip/hip_bf16.h>
#include <math.h>

// LSTM (N=64, T=1024, D=H=512), persistent bf16-MFMA v6.
//
// ws layout:
//   Wt  bf16 [2048][1024] @ 0        (4 MB)   [Wx;Wh]^T, col-major-K
//   hb  bf16 [2][64][512] @ 4MB      (128 KB) h panels, parity-buffered
//   flg u32  [256][16]    @ 4MB+128K (16 KB)  words 0/1 = gate-wave flags
//
// 256 blocks = 4 row-groups (16 rows) x 64 j-groups (8 h-cols x 4 gates).
// 512 thr = 8 waves = 2 col-tiles (ct) x 4 K-quarters (kq); 4 x-MFMA + 4
// h-MFMA per wave. x fragments live in registers (plain cached loads,
// prefetched 1 step ahead). h staged once per block into a 16 KB swizzled
// LDS panel (r8's verified full-rank swizzle). Wave0-only flag poll +
// syncthreads release; dual flags published per gate wave after its own
// vmcnt(0) drain. 3 barriers/step. c-state in registers.

#define TT 1024
#define HH 512
#define FH 2048
#define KK 1024
#define NN 64

typedef __attribute__((ext_vector_type(8))) short bf16x8;
typedef __attribute__((ext_vector_type(4))) float f32x4;
typedef __attribute__((ext_vector_type(4))) int int4v;
typedef __attribute__((ext_vector_type(2))) int int2v;

__device__ __forceinline__ unsigned short f2bf(float f) {
    return __builtin_bit_cast(unsigned short, __float2bfloat16(f));
}

// ---------------- prep: Wt[col][k] = [Wx;Wh]^T bf16 ----------------
__global__ __launch_bounds__(256)
void prep_wt(const float* __restrict__ Wx, const float* __restrict__ Wh,
             unsigned short* __restrict__ Wt)
{
    __shared__ float tile[64][65];
    const int c0  = blockIdx.x * 64;
    const int k0  = blockIdx.y * 64;
    const int tid = threadIdx.x;

    #pragma unroll
    for (int it = 0; it < 16; ++it) {
        int idx = it * 256 + tid;
        int kk = idx >> 6, cc = idx & 63;
        int k = k0 + kk;
        float w = (k < 512) ? Wx[(size_t)k * FH + c0 + cc]
                            : Wh[(size_t)(k - 512) * FH + c0 + cc];
        tile[kk][cc] = w;
    }
    __syncthreads();

    #pragma unroll
    for (int it = 0; it < 8; ++it) {
        int idx = it * 256 + tid;
        int cc = idx >> 5, kp = idx & 31;
        unsigned int lo = f2bf(tile[kp * 2][cc]);
        unsigned int hi = f2bf(tile[kp * 2 + 1][cc]);
        *(unsigned int*)(Wt + (size_t)(c0 + cc) * KK + k0 + kp * 2) =
            lo | (hi << 16);
    }
}

// ---------------- init: zero flags, seed hb parity0 ----------------
__global__ __launch_bounds__(256)
void lstm_init(const float* __restrict__ h0,
               unsigned short* __restrict__ hb,
               unsigned int* __restrict__ flg)
{
    int id = blockIdx.x * 256 + threadIdx.x;
    if (id < 256 * 16) {
        unsigned int* p = flg + id;
        unsigned int z = 0u;
        asm volatile("global_store_dword %0, %1, off sc0 sc1" :: "v"(p), "v"(z) : "memory");
    }
    if (id < NN * HH) {
        unsigned int hv = (unsigned int)f2bf(h0[id]);
        unsigned short* hp = hb + id;
        asm volatile("global_store_short %0, %1, off sc0 sc1" :: "v"(hp), "v"(hv) : "memory");
    }
}

// ---------------- persistent recurrence ----------------
__global__ __launch_bounds__(512)
void lstm_persist(const float* __restrict__ x,
                  const unsigned short* __restrict__ Wt,
                  const float* __restrict__ bias,
                  float* __restrict__ out,
                  unsigned short* __restrict__ hb,
                  unsigned int* __restrict__ flg)
{
    __shared__ __align__(16) unsigned short Aph[16 * 512];  // 16 KB h panel
    __shared__ float part[8][16][17];                        // 8.7 KB partials

    const int tid  = threadIdx.x;
    const int wv   = tid >> 6;
    const int lane = tid & 63;
    const int l15  = lane & 15;
    const int kh   = lane >> 4;            // 0..3

    const int rg = blockIdx.x >> 6;        // row-group 0..3
    const int jg = blockIdx.x & 63;        // j-group 0..63
    const int j0 = jg * 8;
    const int rowbase = rg * 16;

    const int ct = wv & 1;                 // col-tile 0..1
    const int kq = wv >> 1;                // K-quarter 0..3

    const int lc   = ct * 16 + l15;        // local A-col 0..31
    const int gate = lc >> 3;
    const int jj   = lc & 7;
    const int gcol = gate * HH + j0 + jj;

    // ---- hoist B fragments (32 VGPR) ----
    const unsigned short* wtp = Wt + (size_t)gcol * KK + kh * 8;
    bf16x8 bx[4], bh[4];
    #pragma unroll
    for (int ks = 0; ks < 4; ++ks) {
        bx[ks] = *(const bf16x8*)(wtp + kq * 128 + ks * 32);
        bh[ks] = *(const bf16x8*)(wtp + 512 + kq * 128 + ks * 32);
    }

    // x addressing (reg-direct, MFMA layout; redundant across ct pair, L2-cached)
    const float* xlane = x + (size_t)(rowbase + l15) * TT * 512 + kq * 128 + kh * 8;

    // h-panel read addressing (full-rank swizzle, verified in r8)
    const int arow = l15;
    const int rsw  = ((arow & 15) << 3) | ((arow & 3) << 7);

    // h-stage coords: thread (srow = tid>>5, scol = tid&31), 32B each
    const int srow  = tid >> 5;
    const int scol  = tid & 31;
    const int rsw_s = ((srow & 15) << 3) | ((srow & 3) << 7);
    const unsigned short* hrow = hb + (size_t)(rowbase + srow) * HH + scol * 16;
    unsigned short* aps0 = Aph + srow * 512 + ((scol * 16) ^ rsw_s);
    unsigned short* aps1 = Aph + srow * 512 + (((scol * 16) + 8) ^ rsw_s);

    // gate-phase ownership (tid < 128)
    const int grow_l = (tid >> 3) & 15;
    const int q      = tid & 7;
    const int grow   = rowbase + grow_l;
    const int gj     = j0 + q;
    float bi = 0.f, bf_ = 0.f, bo = 0.f, bg = 0.f;
    if (tid < 128) {
        bi  = bias[gj];
        bf_ = bias[HH + gj];
        bo  = bias[2 * HH + gj];
        bg  = bias[3 * HH + gj];
    }
    float c_reg = 0.f;
    float* outp = out + (size_t)grow * TT * HH + gj;
    unsigned short* hdst0 = hb + (size_t)grow * HH + gj;

    unsigned int* myflag = flg + (size_t)blockIdx.x * 16 + wv;   // word 0/1
    const unsigned int* pollp = flg + (size_t)(rg * 64 + lane) * 16;

    // ---- prologue: x fragments for t=0 ----
    int4v xw[8];
    {
        #pragma unroll
        for (int ks = 0; ks < 4; ++ks) {
            asm volatile("global_load_dwordx4 %0, %1, off" : "=v"(xw[2 * ks])     : "v"(xlane + ks * 32));
            asm volatile("global_load_dwordx4 %0, %1, off" : "=v"(xw[2 * ks + 1]) : "v"(xlane + ks * 32 + 4));
        }
        asm volatile("s_waitcnt vmcnt(0)" ::: "memory");
        __builtin_amdgcn_sched_barrier(0);
    }
    bf16x8 xf[4];
    #pragma unroll
    for (int ks = 0; ks < 4; ++ks) {
        float4 u = __builtin_bit_cast(float4, xw[2 * ks]);
        float4 v = __builtin_bit_cast(float4, xw[2 * ks + 1]);
        bf16x8 a;
        a[0] = (short)f2bf(u.x); a[1] = (short)f2bf(u.y);
        a[2] = (short)f2bf(u.z); a[3] = (short)f2bf(u.w);
        a[4] = (short)f2bf(v.x); a[5] = (short)f2bf(v.y);
        a[6] = (short)f2bf(v.z); a[7] = (short)f2bf(v.w);
        xf[ks] = a;
    }

    for (int t = 0; t < TT; ++t) {
        const int pb  = t & 1;
        const int nxt = pb ^ 1;

        // ---- x-GEMM: 4 MFMA from registers (overlaps peers' publish) ----
        f32x4 accx = {0.f, 0.f, 0.f, 0.f};
        #pragma unroll
        for (int ks = 0; ks < 4; ++ks)
            accx = __builtin_amdgcn_mfma_f32_16x16x32_bf16(xf[ks], bx[ks], accx, 0, 0, 0);

        // ---- poll (wave 0 only): both flag words of all 64 producers >= t ----
        if (t > 0 && wv == 0) {
            const unsigned int tgt = (unsigned int)t;
            int2v v;
            do {
                asm volatile("global_load_dwordx2 %0, %1, off sc0 sc1\n\t"
                             "s_waitcnt vmcnt(0)"
                             : "=v"(v) : "v"(pollp) : "memory");
            } while (!__all(((unsigned int)v[0] >= tgt) & ((unsigned int)v[1] >= tgt)));
        }
        __syncthreads();   // B2: release

        // ---- stage h (16 KB once per block): 32B/thread, swizzled LDS ----
        {
            const unsigned short* hs = hrow + (size_t)pb * NN * HH;
            int4v h0v, h1v;
            asm volatile("global_load_dwordx4 %0, %2, off sc0 sc1\n\t"
                         "global_load_dwordx4 %1, %3, off sc0 sc1\n\t"
                         "s_waitcnt vmcnt(0)"
                         : "=&v"(h0v), "=&v"(h1v)
                         : "v"(hs), "v"(hs + 8) : "memory");
            __builtin_amdgcn_sched_barrier(0);
            *(int4v*)aps0 = h0v;
            *(int4v*)aps1 = h1v;
        }
        __syncthreads();   // B3: h panel visible

        // ---- h-GEMM: 4 MFMA from LDS ----
        f32x4 acch = {0.f, 0.f, 0.f, 0.f};
        #pragma unroll
        for (int ks = 0; ks < 4; ++ks) {
            bf16x8 hf = *(const bf16x8*)(Aph + arow * 512
                           + ((kq * 128 + ks * 32 + kh * 8) ^ rsw));
            acch = __builtin_amdgcn_mfma_f32_16x16x32_bf16(hf, bh[ks], acch, 0, 0, 0);
        }
        #pragma unroll
        for (int rr = 0; rr < 4; ++rr)
            part[wv][kh * 4 + rr][l15] = accx[rr] + acch[rr];
        __syncthreads();   // B4: partials ready

        // ---- gates (waves 0-1): direct reduce, state update, publish ----
        if (tid < 128) {
            float Ai = bi, Af = bf_, Ao = bo, Ag = bg;
            #pragma unroll
            for (int k2 = 0; k2 < 4; ++k2) {
                Ai += part[2 * k2][grow_l][q];
                Af += part[2 * k2][grow_l][8 + q];
                Ao += part[2 * k2 + 1][grow_l][q];
                Ag += part[2 * k2 + 1][grow_l][8 + q];
            }
            float ig = 1.f / (1.f + __expf(-Ai));
            float fg = 1.f / (1.f + __expf(-Af));
            float og = 1.f / (1.f + __expf(-Ao));
            float eg = __expf(2.f * Ag);
            float gg = 1.f - 2.f / (eg + 1.f);          // tanh(Ag)
            c_reg = fg * c_reg + ig * gg;
            float ec = __expf(2.f * c_reg);
            float tc = 1.f - 2.f / (ec + 1.f);          // tanh(c)
            float hn = og * tc;

            unsigned int hv = (unsigned int)f2bf(hn);
            unsigned short* hdst = hdst0 + (size_t)nxt * NN * HH;
            asm volatile("global_store_short %0, %1, off sc0 sc1"
                         :: "v"(hdst), "v"(hv) : "memory");
            asm volatile("s_waitcnt vmcnt(0)" ::: "memory");   // drain own h stores
            if (t + 1 < TT && lane == 0) {
                unsigned int tgt2 = (unsigned int)(t + 1);
                asm volatile("global_store_dword %0, %1, off sc0 sc1"
                             :: "v"(myflag), "v"(tgt2) : "memory");
            }
            outp[(size_t)t * HH] = hn;   // off critical path, after publish
        }

        // ---- x prefetch + convert for t+1 (all waves; overlaps peers) ----
        if (t + 1 < TT) {
            const float* xp = xlane + (size_t)(t + 1) * 512;
            #pragma unroll
            for (int ks = 0; ks < 4; ++ks) {
                asm volatile("global_load_dwordx4 %0, %1, off" : "=v"(xw[2 * ks])     : "v"(xp + ks * 32));
                asm volatile("global_load_dwordx4 %0, %1, off" : "=v"(xw[2 * ks + 1]) : "v"(xp + ks * 32 + 4));
            }
            asm volatile("s_waitcnt vmcnt(0)" ::: "memory");
            __builtin_amdgcn_sched_barrier(0);
            #pragma unroll
            for (int ks = 0; ks < 4; ++ks) {
                float4 u = __builtin_bit_cast(float4, xw[2 * ks]);
                float4 v = __builtin_bit_cast(float4, xw[2 * ks + 1]);
                bf16x8 a;
                a[0] = (short)f2bf(u.x); a[1] = (short)f2bf(u.y);
                a[2] = (short)f2bf(u.z); a[3] = (short)f2bf(u.w);
                a[4] = (short)f2bf(v.x); a[5] = (short)f2bf(v.y);
                a[6] = (short)f2bf(v.z); a[7] = (short)f2bf(v.w);
                xf[ks] = a;
            }
        }
    }
}

extern "C" void kernel_launch(void* const* d_in, const int* in_sizes, int n_in,
                              void* d_out, int out_size, void* d_ws, size_t ws_size,
                              hipStream_t stream)
{
    const float* x  = (const float*)d_in[0];
    const float* h0 = (const float*)d_in[1];
    const float* Wx = (const float*)d_in[2];
    const float* Wh = (const float*)d_in[3];
    const float* b  = (const float*)d_in[4];
    float* out = (float*)d_out;

    char* ws = (char*)d_ws;
    unsigned short* Wt  = (unsigned short*)ws;                                      // 4 MB
    unsigned short* hb  = (unsigned short*)(ws + (size_t)4 * 1024 * 1024);          // 128 KB
    unsigned int*   flg = (unsigned int*)(ws + (size_t)4 * 1024 * 1024 + 131072);   // 16 KB

    prep_wt<<<dim3(32, 16), 256, 0, stream>>>(Wx, Wh, Wt);
    lstm_init<<<128, 256, 0, stream>>>(h0, hb, flg);
    lstm_persist<<<256, 512, 0, stream>>>(x, Wt, b, out, hb, flg);
}